// Round 4
// baseline (414.472 us; speedup 1.0000x reference)
//
#include <hip/hip_runtime.h>
#include <math.h>

#define B_ 64
#define N_ 16384
#define K_ 8
#define SCALE 0.125f          // 1/sqrt(64)
#define LN_EPS 1e-5f
#define CHUNKS 4
#define ROWS_PER_CHUNK (N_ / CHUNKS)   // 4096
#define TILE 256
#define TILES (ROWS_PER_CHUNK / TILE)  // 16
#define CHSTR 260             // floats per 4-row chunk (1024B + 16B pad)
#define REC 528               // record: 512 Y + 8 S + 8 t1

__device__ __forceinline__ float wsum64(float v) {
#pragma unroll
  for (int m = 1; m < 64; m <<= 1) v += __shfl_xor(v, m);
  return v;
}

// async global->LDS, 16B/lane; LDS dest = wave-uniform base + lane*16
__device__ __forceinline__ void dma16(const float* g, float* l) {
  __builtin_amdgcn_global_load_lds(
      (const __attribute__((address_space(1))) float*)g,
      (__attribute__((address_space(3))) float*)l, 16, 0, 0);
}

// slots = mu + sigma * noise   (32768 elems)
__global__ void init_slots(const float* __restrict__ noise, const float* __restrict__ mu,
                           const float* __restrict__ sg, float* __restrict__ slots) {
  int i = blockIdx.x * blockDim.x + threadIdx.x;
  int d = i & 63;
  slots[i] = mu[d] + sg[d] * noise[i];
}

// Per (b,kk): q = LN(slots; ln_slots)@wq + bq ; fold through wk and input-LN affine.
__global__ __launch_bounds__(64) void prep_q(
    const float* __restrict__ slots,
    const float* __restrict__ lnsw, const float* __restrict__ lnsb,
    const float* __restrict__ wq, const float* __restrict__ bq,
    const float* __restrict__ wk, const float* __restrict__ bk,
    const float* __restrict__ lniw, const float* __restrict__ lnib,
    float* __restrict__ qprep) {
  const int bk_i = blockIdx.x;            // b*8+kk
  const int b = bk_i >> 3, kk = bk_i & 7;
  const int d = threadIdx.x;
  __shared__ float xs[64], qsh[64], wkl[64 * 65];
  for (int i = 0; i < 64; ++i) wkl[i * 65 + d] = wk[i * 64 + d];
  float s = slots[bk_i * 64 + d];
  float m = wsum64(s) * (1.f / 64.f);
  float df = s - m;
  float var = wsum64(df * df) * (1.f / 64.f);
  float r = 1.f / sqrtf(var + LN_EPS);
  xs[d] = df * r * lnsw[d] + lnsb[d];
  __syncthreads();
  float q = bq[d];
  for (int c = 0; c < 64; ++c) q += xs[c] * wq[c * 64 + d];
  qsh[d] = q;
  __syncthreads();
  float qp = 0.f, c0 = 0.f;
  for (int dd = 0; dd < 64; ++dd) {
    float qd = qsh[dd];
    qp += wkl[d * 65 + dd] * qd;
    c0 += qd * bk[dd];
  }
  float qw = qp * lniw[d] * SCALE;
  float As = wsum64(qw);
  float Bp = wsum64(qp * lnib[d]);
  float Bc = (Bp + c0) * SCALE;
  float* rec = qprep + b * REC;
  rec[d * 8 + kk] = qw;                   // qwT[c][kk]
  if (d == 0) { rec[512 + kk] = As; rec[520 + kk] = Bc; }
}

// Streaming pass: grid = 256 blocks x 256 threads, 1 block/CU (LDS-limited).
// Double-buffered padded-chunk LDS tiles via global_load_lds (linear, 16B pad
// per 1KB chunk kills all bank conflicts); counted vmcnt keeps next tile's
// DMA in flight; qw coefficients come from the scalar cache (wave-uniform).
__global__ __launch_bounds__(256) void attn_pass(
    const float* __restrict__ inp, const float* __restrict__ qprep,
    float* __restrict__ part) {
  __shared__ __align__(16) float xbuf[2][64 * CHSTR];  // 133120 B
  __shared__ __align__(16) float awb[256 * 10];        // 10240 B (a*r, 8/row, pad 10)
  __shared__ float redST[64];
  const int tid = threadIdx.x;
  const int w = tid >> 6, lane = tid & 63;
  const int b = blockIdx.x >> 2, chunk4 = blockIdx.x & 3;
  const float* __restrict__ qp = qprep + b * REC;      // uniform -> s_load
  const float* srcbase = inp + ((size_t)b * N_ + (size_t)chunk4 * ROWS_PER_CHUNK) * 64;
  float As_[8], Bc_[8];
#pragma unroll
  for (int kq = 0; kq < 8; ++kq) { As_[kq] = qp[512 + kq]; Bc_[kq] = qp[520 + kq]; }
  // prologue: DMA tile 0 into buf 0 (wave w owns chunks w*16..w*16+15)
#pragma unroll
  for (int i = 0; i < 16; ++i) {
    const int ch = w * 16 + i;
    dma16(srcbase + ch * 256 + lane * 4, &xbuf[0][ch * CHSTR]);
  }
  const int R = tid;                       // phase A: full row per thread
  const int g = lane >> 4, q = lane & 15;  // phase B: quad-row mapping
  float Ya[8][4];
  float sS[8], sT[8];
#pragma unroll
  for (int kq = 0; kq < 8; ++kq) {
    sS[kq] = 0.f; sT[kq] = 0.f;
#pragma unroll
    for (int e = 0; e < 4; ++e) Ya[kq][e] = 0.f;
  }
  for (int t = 0; t < TILES; ++t) {
    const int cur = t & 1;
    asm volatile("s_waitcnt lgkmcnt(0)" ::: "memory");
    __builtin_amdgcn_s_barrier();          // bar1: frees buf[cur^1] + awb
    __builtin_amdgcn_sched_barrier(0);
    if (t + 1 < TILES) {
      const float* tb = srcbase + (size_t)(t + 1) * TILE * 64;
      float* lb = &xbuf[cur ^ 1][0];
#pragma unroll
      for (int i = 0; i < 16; ++i) {
        const int ch = w * 16 + i;
        dma16(tb + ch * 256 + lane * 4, lb + ch * CHSTR);
      }
      asm volatile("s_waitcnt vmcnt(16)" ::: "memory");  // tile t done, t+1 in flight
    } else {
      asm volatile("s_waitcnt vmcnt(0)" ::: "memory");
    }
    __builtin_amdgcn_sched_barrier(0);
    __builtin_amdgcn_s_barrier();          // bar2: buf[cur] ready
    // ---- phase A: full row R; qw via scalar loads; zero LDS for coeffs ----
    const float* rowp = &xbuf[cur][(R >> 2) * CHSTR + (R & 3) * 64];
    float sum = 0.f, sq = 0.f;
    float l[8] = {0, 0, 0, 0, 0, 0, 0, 0};
#pragma unroll
    for (int j = 0; j < 16; ++j) {
      const float4 xv = *reinterpret_cast<const float4*>(rowp + j * 4);
      const float xc[4] = {xv.x, xv.y, xv.z, xv.w};
#pragma unroll
      for (int e = 0; e < 4; ++e) {
        const int c = j * 4 + e;
        const float v = xc[e];
        sum += v; sq += v * v;
#pragma unroll
        for (int kq = 0; kq < 8; ++kq) l[kq] += qp[c * 8 + kq] * v;
      }
    }
    const float m = sum * (1.f / 64.f);
    const float var = sq * (1.f / 64.f) - m * m;
    const float r = 1.f / sqrtf(var + LN_EPS);
    const float mr = m * r;
    float lmax = -1e30f;
#pragma unroll
    for (int kq = 0; kq < 8; ++kq) {
      l[kq] = r * l[kq] - mr * As_[kq] + Bc_[kq];
      lmax = fmaxf(lmax, l[kq]);
    }
    float es = 0.f;
#pragma unroll
    for (int kq = 0; kq < 8; ++kq) { l[kq] = __expf(l[kq] - lmax); es += l[kq]; }
    const float inv = 1.f / es;
#pragma unroll
    for (int kq = 0; kq < 8; ++kq) {
      const float a = l[kq] * inv;
      sS[kq] += a;
      sT[kq] += a * mr;
      l[kq] = a * r;
    }
    *reinterpret_cast<float4*>(&awb[R * 10])     = make_float4(l[0], l[1], l[2], l[3]);
    *reinterpret_cast<float4*>(&awb[R * 10 + 4]) = make_float4(l[4], l[5], l[6], l[7]);
    asm volatile("s_waitcnt lgkmcnt(0)" ::: "memory");
    __builtin_amdgcn_s_barrier();          // bar3: awb visible
    // ---- phase B: wave w chunks w*16..+15; lane (g,q): row=4ch+g, cols q*4..+3 ----
#pragma unroll 4
    for (int i = 0; i < 16; ++i) {
      const int chb = w * 16 + i;
      const float* ap = &awb[(chb * 4 + g) * 10];
      const float4 a0 = *reinterpret_cast<const float4*>(ap);
      const float4 a1 = *reinterpret_cast<const float4*>(ap + 4);
      const float4 xv = *reinterpret_cast<const float4*>(
          &xbuf[cur][chb * CHSTR + g * 64 + (q << 2)]);
      const float xc[4] = {xv.x, xv.y, xv.z, xv.w};
#pragma unroll
      for (int e = 0; e < 4; ++e) {
        Ya[0][e] += a0.x * xc[e]; Ya[1][e] += a0.y * xc[e];
        Ya[2][e] += a0.z * xc[e]; Ya[3][e] += a0.w * xc[e];
        Ya[4][e] += a1.x * xc[e]; Ya[5][e] += a1.y * xc[e];
        Ya[6][e] += a1.z * xc[e]; Ya[7][e] += a1.w * xc[e];
      }
    }
  }
  // ---- epilogue (once): reduce Ya over (w,g); S/T over threads ----
#pragma unroll
  for (int kq = 0; kq < 8; ++kq) { sS[kq] = wsum64(sS[kq]); sT[kq] = wsum64(sT[kq]); }
  if (lane == 0) {
#pragma unroll
    for (int i = 0; i < 8; ++i) { redST[w * 16 + i] = sS[i]; redST[w * 16 + 8 + i] = sT[i]; }
  }
  float* yr = &xbuf[0][0];
#pragma unroll
  for (int kq = 0; kq < 8; ++kq)
    *reinterpret_cast<float4*>(yr + tid * 36 + kq * 4) =
        make_float4(Ya[kq][0], Ya[kq][1], Ya[kq][2], Ya[kq][3]);
  __syncthreads();
  float* dst = part + (size_t)blockIdx.x * REC;
  for (int o = tid; o < 512; o += 256) {
    const int kq = o >> 6, col = o & 63;
    const int qq = col >> 2, ee = col & 3;
    float v = 0.f;
#pragma unroll
    for (int s = 0; s < 16; ++s) v += yr[(s * 16 + qq) * 36 + kq * 4 + ee];
    dst[o] = v;
  }
  if (tid < 16)
    dst[512 + tid] = redST[tid] + redST[16 + tid] + redST[32 + tid] + redST[48 + tid];
}

// Fused: partial-reduce -> updates -> GRU -> LN -> MLP -> new slots -> q-prep(next).
__global__ __launch_bounds__(256) void slot_update(
    const float* __restrict__ part, const float* slots_in,
    const float* __restrict__ lniw, const float* __restrict__ lnib,
    const float* __restrict__ wv, const float* __restrict__ bv,
    const float* __restrict__ wih, const float* __restrict__ bih,
    const float* __restrict__ whh, const float* __restrict__ bhh,
    const float* __restrict__ lnfw, const float* __restrict__ lnfb,
    const float* __restrict__ w1, const float* __restrict__ b1,
    const float* __restrict__ w2, const float* __restrict__ b2,
    const float* __restrict__ lnsw, const float* __restrict__ lnsb,
    const float* __restrict__ wq, const float* __restrict__ bq,
    const float* __restrict__ wk, const float* __restrict__ bkv,
    float* slots_out, float* __restrict__ qprep, const int do_prep) {
  const int bk_i = blockIdx.x, b = bk_i >> 3, kk = bk_i & 7;
  const int tid = threadIdx.x, cq = tid >> 6, d = tid & 63;
  const int c0 = cq * 16;
  __shared__ float pA[4][68], pB[4][68], pC[4][68], pD[4][68];
  __shared__ float xsh[64], psh[64], ush[64], hsh[64], snsh[64], qsh[64];
  __shared__ float hid1[2][132];
  const float* pb = part + (size_t)(b * CHUNKS) * REC;
  float S = 0.f, T1 = 0.f;
#pragma unroll
  for (int ch = 0; ch < CHUNKS; ++ch) {
    S += pb[ch * REC + 512 + kk];
    T1 += pb[ch * REC + 520 + kk];
  }
  pA[cq][d] = pb[cq * REC + kk * 64 + d];        // one chunk per cq
  const float prev = slots_in[bk_i * 64 + d];
  if (cq == 0) psh[d] = prev;
  __syncthreads();                               // s1
  if (cq == 0) {
    const float Y = pA[0][d] + pA[1][d] + pA[2][d] + pA[3][d];
    xsh[d] = lniw[d] * (Y - T1) + lnib[d] * S;
  }
  __syncthreads();                               // s2
  {
    float up = 0.f, h0 = 0.f, h1 = 0.f, h2 = 0.f;
    for (int c = c0; c < c0 + 16; ++c) {
      const float xc = xsh[c], pc = psh[c];
      up += wv[c * 64 + d] * xc;
      h0 += pc * whh[c * 192 + d];
      h1 += pc * whh[c * 192 + 64 + d];
      h2 += pc * whh[c * 192 + 128 + d];
    }
    pA[cq][d] = up; pB[cq][d] = h0; pC[cq][d] = h1; pD[cq][d] = h2;
  }
  __syncthreads();                               // s3
  float hh0 = 0.f, hh1 = 0.f, hh2 = 0.f;
  if (cq == 0) {
    ush[d] = S * bv[d] + pA[0][d] + pA[1][d] + pA[2][d] + pA[3][d];
    hh0 = bhh[d] + pB[0][d] + pB[1][d] + pB[2][d] + pB[3][d];
    hh1 = bhh[64 + d] + pC[0][d] + pC[1][d] + pC[2][d] + pC[3][d];
    hh2 = bhh[128 + d] + pD[0][d] + pD[1][d] + pD[2][d] + pD[3][d];
  }
  __syncthreads();                               // s4
  {
    float g0 = 0.f, g1 = 0.f, g2 = 0.f;
    for (int c = c0; c < c0 + 16; ++c) {
      const float uc = ush[c];
      g0 += uc * wih[c * 192 + d];
      g1 += uc * wih[c * 192 + 64 + d];
      g2 += uc * wih[c * 192 + 128 + d];
    }
    pA[cq][d] = g0; pB[cq][d] = g1; pC[cq][d] = g2;
  }
  __syncthreads();                               // s5
  if (cq == 0) {
    const float gi0 = bih[d] + pA[0][d] + pA[1][d] + pA[2][d] + pA[3][d];
    const float gi1 = bih[64 + d] + pB[0][d] + pB[1][d] + pB[2][d] + pB[3][d];
    const float gi2 = bih[128 + d] + pC[0][d] + pC[1][d] + pC[2][d] + pC[3][d];
    const float rg = 1.f / (1.f + __expf(-(gi0 + hh0)));
    const float zg = 1.f / (1.f + __expf(-(gi1 + hh1)));
    const float ng = tanhf(gi2 + rg * hh2);
    const float sn = (1.f - zg) * ng + zg * prev;
    const float mm = wsum64(sn) * (1.f / 64.f);
    const float df = sn - mm;
    const float vv = wsum64(df * df) * (1.f / 64.f);
    const float rr = 1.f / sqrtf(vv + LN_EPS);
    snsh[d] = sn;
    hsh[d] = df * rr * lnfw[d] + lnfb[d];
  }
  __syncthreads();                               // s6
  {
    const int j = tid & 127, ch2 = tid >> 7;
    float a = 0.f;
    for (int c = ch2 * 32; c < ch2 * 32 + 32; ++c) a += hsh[c] * w1[c * 128 + j];
    hid1[ch2][j] = a;
  }
  __syncthreads();                               // s7
  {
    float o = 0.f;
    for (int j2 = cq * 32; j2 < cq * 32 + 32; ++j2) {
      const float hv = fmaxf(hid1[0][j2] + hid1[1][j2] + b1[j2], 0.f);
      o += hv * w2[j2 * 64 + d];
    }
    pA[cq][d] = o;
  }
  __syncthreads();                               // s8
  float news = 0.f;
  if (cq == 0) {
    news = snsh[d] + b2[d] + pA[0][d] + pA[1][d] + pA[2][d] + pA[3][d];
    slots_out[bk_i * 64 + d] = news;
  }
  if (!do_prep) return;
  // ---- fused q-prep for next iteration ----
  if (cq == 0) {
    const float mm = wsum64(news) * (1.f / 64.f);
    const float df = news - mm;
    const float vv = wsum64(df * df) * (1.f / 64.f);
    const float rr = 1.f / sqrtf(vv + LN_EPS);
    xsh[d] = df * rr * lnsw[d] + lnsb[d];
  }
  __syncthreads();                               // s9
  {
    float qpt = 0.f;
    for (int c = c0; c < c0 + 16; ++c) qpt += xsh[c] * wq[c * 64 + d];
    pB[cq][d] = qpt;
  }
  __syncthreads();                               // s10
  if (cq == 0) qsh[d] = bq[d] + pB[0][d] + pB[1][d] + pB[2][d] + pB[3][d];
  __syncthreads();                               // s11
  {
    float qq = 0.f;
    for (int dd2 = c0; dd2 < c0 + 16; ++dd2) qq += wk[d * 64 + dd2] * qsh[dd2];
    pC[cq][d] = qq;
  }
  __syncthreads();                               // s12
  if (cq == 0) {
    const float qpv = pC[0][d] + pC[1][d] + pC[2][d] + pC[3][d];
    const float c0v = wsum64(qsh[d] * bkv[d]);
    const float qw = qpv * lniw[d] * SCALE;
    const float As = wsum64(qw);
    const float Bp = wsum64(qpv * lnib[d]);
    const float Bc = (Bp + c0v) * SCALE;
    float* rec = qprep + b * REC;
    rec[d * 8 + kk] = qw;
    if (d == 0) { rec[512 + kk] = As; rec[520 + kk] = Bc; }
  }
}

extern "C" void kernel_launch(void* const* d_in, const int* in_sizes, int n_in,
                              void* d_out, int out_size, void* d_ws, size_t ws_size,
                              hipStream_t stream) {
  const float* inp   = (const float*)d_in[0];
  const float* noise = (const float*)d_in[1];
  const float* mu    = (const float*)d_in[2];
  const float* sg    = (const float*)d_in[3];
  const float* lniw  = (const float*)d_in[4];
  const float* lnib  = (const float*)d_in[5];
  const float* lnsw  = (const float*)d_in[6];
  const float* lnsb  = (const float*)d_in[7];
  const float* lnfw  = (const float*)d_in[8];
  const float* lnfb  = (const float*)d_in[9];
  const float* wk    = (const float*)d_in[10];
  const float* bk    = (const float*)d_in[11];
  const float* wq    = (const float*)d_in[12];
  const float* bq    = (const float*)d_in[13];
  const float* wv    = (const float*)d_in[14];
  const float* bv    = (const float*)d_in[15];
  const float* wih   = (const float*)d_in[16];
  const float* bih   = (const float*)d_in[17];
  const float* whh   = (const float*)d_in[18];
  const float* bhh   = (const float*)d_in[19];
  const float* w1    = (const float*)d_in[20];
  const float* b1    = (const float*)d_in[21];
  const float* w2    = (const float*)d_in[22];
  const float* b2    = (const float*)d_in[23];
  float* ws = (float*)d_ws;
  float* slots = ws;                              // 32768
  float* qprep = ws + 32768;                      // 64*528 = 33792
  float* part  = ws + 32768 + 64 * REC;           // 256*528 = 135168
  float* out   = (float*)d_out;
  init_slots<<<64, 512, 0, stream>>>(noise, mu, sg, slots);
  prep_q<<<B_ * K_, 64, 0, stream>>>(slots, lnsw, lnsb, wq, bq, wk, bk, lniw, lnib, qprep);
  for (int it = 0; it < 3; ++it) {
    attn_pass<<<B_ * CHUNKS, 256, 0, stream>>>(inp, qprep, part);
    slot_update<<<B_ * K_, 256, 0, stream>>>(
        part, slots, lniw, lnib, wv, bv, wih, bih, whh, bhh,
        lnfw, lnfb, w1, b1, w2, b2, lnsw, lnsb, wq, bq, wk, bk,
        (it == 2) ? out : slots, qprep, (it < 2) ? 1 : 0);
  }
}

// Round 7
// 319.304 us; speedup vs baseline: 1.2980x; 1.2980x over previous
//
#include <hip/hip_runtime.h>
#include <math.h>

#define B_ 64
#define N_ 16384
#define K_ 8
#define SCALE 0.125f          // 1/sqrt(64)
#define LN_EPS 1e-5f
#define CHUNKS 16
#define REC 528               // record: 512 Y + 8 S + 8 t1

typedef unsigned int u32;
typedef __fp16 half2_t __attribute__((ext_vector_type(2)));

__device__ __forceinline__ float wsum64(float v) {
#pragma unroll
  for (int m = 1; m < 64; m <<= 1) v += __shfl_xor(v, m);
  return v;
}

// pack two f32 -> two fp16 (RTZ) in one u32
__device__ __forceinline__ u32 pk16(float a, float b) {
  half2_t h = __builtin_amdgcn_cvt_pkrtz(a, b);
  return __builtin_bit_cast(u32, h);
}
// unpack u32 of two fp16 -> float2
__device__ __forceinline__ float2 up16(u32 u) {
  half2_t h = __builtin_bit_cast(half2_t, u);
  return make_float2((float)h.x, (float)h.y);
}

// slots = mu + sigma * noise   (32768 elems)
__global__ void init_slots(const float* __restrict__ noise, const float* __restrict__ mu,
                           const float* __restrict__ sg, float* __restrict__ slots) {
  int i = blockIdx.x * blockDim.x + threadIdx.x;
  int d = i & 63;
  slots[i] = mu[d] + sg[d] * noise[i];
}

// Per (b,kk): q = LN(slots; ln_slots)@wq + bq ; fold through wk and input-LN affine.
__global__ __launch_bounds__(64) void prep_q(
    const float* __restrict__ slots,
    const float* __restrict__ lnsw, const float* __restrict__ lnsb,
    const float* __restrict__ wq, const float* __restrict__ bq,
    const float* __restrict__ wk, const float* __restrict__ bk,
    const float* __restrict__ lniw, const float* __restrict__ lnib,
    float* __restrict__ qprep) {
  const int bk_i = blockIdx.x;            // b*8+kk
  const int b = bk_i >> 3, kk = bk_i & 7;
  const int d = threadIdx.x;
  __shared__ float xs[64], qsh[64], wkl[64 * 65];
  for (int i = 0; i < 64; ++i) wkl[i * 65 + d] = wk[i * 64 + d];
  float s = slots[bk_i * 64 + d];
  float m = wsum64(s) * (1.f / 64.f);
  float df = s - m;
  float var = wsum64(df * df) * (1.f / 64.f);
  float r = 1.f / sqrtf(var + LN_EPS);
  xs[d] = df * r * lnsw[d] + lnsb[d];
  __syncthreads();
  float q = bq[d];
  for (int c = 0; c < 64; ++c) q += xs[c] * wq[c * 64 + d];
  qsh[d] = q;
  __syncthreads();
  float qp = 0.f, c0 = 0.f;
  for (int dd = 0; dd < 64; ++dd) {
    float qd = qsh[dd];
    qp += wkl[d * 65 + dd] * qd;
    c0 += qd * bk[dd];
  }
  float qw = qp * lniw[d] * SCALE;
  float As = wsum64(qw);
  float Bp = wsum64(qp * lnib[d]);
  float Bc = (Bp + c0) * SCALE;
  float* rec = qprep + b * REC;
  rec[d * 8 + kk] = qw;                   // qwT[c][kk]
  if (d == 0) { rec[512 + kk] = As; rec[520 + kk] = Bc; }
}

// Streaming pass: grid = B*16 = 1024 blocks x 256 threads, 4 blocks/CU
// (16 waves/CU). Wave-private 64-row microtiles: phase A consumes global
// float4s into logits+softmax and stages x as fp16 pairs in LDS; phase B
// re-reads the microtile (conflict-free b64) accumulating Y in registers.
// No block barriers in the loop — ordering is intra-wave.
__global__ __launch_bounds__(256, 4) void attn_pass(
    const float* __restrict__ inp, const float* __restrict__ qprep,
    float* __restrict__ part) {
  __shared__ u32 xls[4][64 * 34];   // fp16 pairs; row stride 34 u32 = 136 B
  __shared__ u32 awl[4][64 * 5];    // a*r fp16 pairs; row stride 5 u32 = 20 B
  __shared__ float redST[64];
  const int tid = threadIdx.x;
  const int w = tid >> 6, lane = tid & 63;
  const int b = blockIdx.x >> 4, chunk = blockIdx.x & 15;
  const float* __restrict__ qp = qprep + b * REC;      // uniform -> s_load
  const float* srcw = inp + ((size_t)b * N_ + (size_t)(chunk * 1024 + w * 256)) * 64;
  float As_[8], Bc_[8];
#pragma unroll
  for (int kq = 0; kq < 8; ++kq) { As_[kq] = qp[512 + kq]; Bc_[kq] = qp[520 + kq]; }
  u32* __restrict__ xw = xls[w];
  u32* __restrict__ aww = awl[w];
  const int rh = lane >> 5, kh = (lane >> 3) & 3, c8 = lane & 7;
  float Y0[8] = {0, 0, 0, 0, 0, 0, 0, 0};
  float Y1[8] = {0, 0, 0, 0, 0, 0, 0, 0};
  float sS[8] = {0, 0, 0, 0, 0, 0, 0, 0};
  float sT[8] = {0, 0, 0, 0, 0, 0, 0, 0};
  for (int mt = 0; mt < 4; ++mt) {
    // ---- phase A: lane owns one row; stream-consume 4 cols at a time ----
    const float4* src = reinterpret_cast<const float4*>(srcw + (size_t)(mt * 64 + lane) * 64);
    float sum = 0.f, sq = 0.f;
    float l[8] = {0, 0, 0, 0, 0, 0, 0, 0};
#pragma unroll
    for (int j = 0; j < 16; ++j) {
      const float4 xv = src[j];
      const float xc[4] = {xv.x, xv.y, xv.z, xv.w};
#pragma unroll
      for (int e = 0; e < 4; ++e) {
        const int c = j * 4 + e;
        const float v = xc[e];
        sum += v; sq += v * v;
#pragma unroll
        for (int kq = 0; kq < 8; ++kq) l[kq] += qp[c * 8 + kq] * v;
      }
      *reinterpret_cast<uint2*>(&xw[lane * 34 + j * 2]) =
          make_uint2(pk16(xv.x, xv.y), pk16(xv.z, xv.w));
    }
    const float m = sum * (1.f / 64.f);
    const float var = sq * (1.f / 64.f) - m * m;
    const float r = 1.f / sqrtf(var + LN_EPS);
    const float mr = m * r;
    float lmax = -1e30f;
#pragma unroll
    for (int kq = 0; kq < 8; ++kq) {
      l[kq] = r * l[kq] - mr * As_[kq] + Bc_[kq];
      lmax = fmaxf(lmax, l[kq]);
    }
    float es = 0.f;
#pragma unroll
    for (int kq = 0; kq < 8; ++kq) { l[kq] = __expf(l[kq] - lmax); es += l[kq]; }
    const float inv = 1.f / es;
#pragma unroll
    for (int kq = 0; kq < 8; ++kq) {
      const float a = l[kq] * inv;
      sS[kq] += a;
      sT[kq] += a * mr;
      l[kq] = a * r;                   // a*r for the Y accumulation
    }
#pragma unroll
    for (int kh2 = 0; kh2 < 4; ++kh2)
      aww[lane * 5 + kh2] = pk16(l[2 * kh2], l[2 * kh2 + 1]);
    // ---- phase B: lane (rh,kh,c8): rows rh*32..+31, kk={2kh,2kh+1}, cols c8*8..+7 ----
    // (compiler inserts the intra-wave lgkmcnt ordering for the RAW on xw/aww)
#pragma unroll 4
    for (int i = 0; i < 32; ++i) {
      const int row = rh * 32 + i;
      const float2 ap = up16(aww[row * 5 + kh]);
      const uint2 q0 = *reinterpret_cast<const uint2*>(&xw[row * 34 + c8 * 4]);
      const uint2 q1 = *reinterpret_cast<const uint2*>(&xw[row * 34 + c8 * 4 + 2]);
      const u32 uu[4] = {q0.x, q0.y, q1.x, q1.y};
#pragma unroll
      for (int t = 0; t < 4; ++t) {
        const float2 xp = up16(uu[t]);
        Y0[2 * t]     += ap.x * xp.x;  Y0[2 * t + 1] += ap.x * xp.y;
        Y1[2 * t]     += ap.y * xp.x;  Y1[2 * t + 1] += ap.y * xp.y;
      }
    }
  }
  // ---- epilogue ----
#pragma unroll
  for (int kq = 0; kq < 8; ++kq) { sS[kq] = wsum64(sS[kq]); sT[kq] = wsum64(sT[kq]); }
  if (lane == 0) {
#pragma unroll
    for (int i = 0; i < 8; ++i) { redST[w * 16 + i] = sS[i]; redST[w * 16 + 8 + i] = sT[i]; }
  }
#pragma unroll
  for (int e = 0; e < 8; ++e) {
    Y0[e] += __shfl_xor(Y0[e], 32);
    Y1[e] += __shfl_xor(Y1[e], 32);
  }
  float* yr = reinterpret_cast<float*>(xw);   // reuse this wave's x region
  if (lane < 32) {
#pragma unroll
    for (int e = 0; e < 8; ++e) {
      yr[(2 * kh + 0) * 64 + c8 * 8 + e] = Y0[e];
      yr[(2 * kh + 1) * 64 + c8 * 8 + e] = Y1[e];
    }
  }
  __syncthreads();
  float* dst = part + (size_t)blockIdx.x * REC;
  for (int o = tid; o < 512; o += 256) {
    float v = 0.f;
#pragma unroll
    for (int ww = 0; ww < 4; ++ww) v += reinterpret_cast<const float*>(xls[ww])[o];
    dst[o] = v;
  }
  if (tid < 16)
    dst[512 + tid] = redST[tid] + redST[16 + tid] + redST[32 + tid] + redST[48 + tid];
}

// Fused: partial-reduce -> updates -> GRU -> LN -> MLP -> new slots -> q-prep(next).
__global__ __launch_bounds__(256) void slot_update(
    const float* __restrict__ part, const float* slots_in,
    const float* __restrict__ lniw, const float* __restrict__ lnib,
    const float* __restrict__ wv, const float* __restrict__ bv,
    const float* __restrict__ wih, const float* __restrict__ bih,
    const float* __restrict__ whh, const float* __restrict__ bhh,
    const float* __restrict__ lnfw, const float* __restrict__ lnfb,
    const float* __restrict__ w1, const float* __restrict__ b1,
    const float* __restrict__ w2, const float* __restrict__ b2,
    const float* __restrict__ lnsw, const float* __restrict__ lnsb,
    const float* __restrict__ wq, const float* __restrict__ bq,
    const float* __restrict__ wk, const float* __restrict__ bkv,
    float* slots_out, float* __restrict__ qprep, const int do_prep) {
  const int bk_i = blockIdx.x, b = bk_i >> 3, kk = bk_i & 7;
  const int tid = threadIdx.x, cq = tid >> 6, d = tid & 63;
  const int c0 = cq * 16;
  __shared__ float pA[4][68], pB[4][68], pC[4][68], pD[4][68];
  __shared__ float xsh[64], psh[64], ush[64], hsh[64], snsh[64], qsh[64];
  __shared__ float hid1[2][132];
  const float* pb = part + (size_t)(b * CHUNKS) * REC;
  float S = 0.f, T1 = 0.f;
#pragma unroll
  for (int ch = 0; ch < CHUNKS; ++ch) {
    S += pb[ch * REC + 512 + kk];
    T1 += pb[ch * REC + 520 + kk];
  }
  {
    float y = 0.f;
#pragma unroll
    for (int cc = 0; cc < 4; ++cc)
      y += pb[(size_t)(cq * 4 + cc) * REC + kk * 64 + d];
    pA[cq][d] = y;
  }
  const float prev = slots_in[bk_i * 64 + d];
  if (cq == 0) psh[d] = prev;
  __syncthreads();                               // s1
  if (cq == 0) {
    const float Y = pA[0][d] + pA[1][d] + pA[2][d] + pA[3][d];
    xsh[d] = lniw[d] * (Y - T1) + lnib[d] * S;
  }
  __syncthreads();                               // s2
  {
    float up = 0.f, h0 = 0.f, h1 = 0.f, h2 = 0.f;
    for (int c = c0; c < c0 + 16; ++c) {
      const float xc = xsh[c], pc = psh[c];
      up += wv[c * 64 + d] * xc;
      h0 += pc * whh[c * 192 + d];
      h1 += pc * whh[c * 192 + 64 + d];
      h2 += pc * whh[c * 192 + 128 + d];
    }
    pA[cq][d] = up; pB[cq][d] = h0; pC[cq][d] = h1; pD[cq][d] = h2;
  }
  __syncthreads();                               // s3
  float hh0 = 0.f, hh1 = 0.f, hh2 = 0.f;
  if (cq == 0) {
    ush[d] = S * bv[d] + pA[0][d] + pA[1][d] + pA[2][d] + pA[3][d];
    hh0 = bhh[d] + pB[0][d] + pB[1][d] + pB[2][d] + pB[3][d];
    hh1 = bhh[64 + d] + pC[0][d] + pC[1][d] + pC[2][d] + pC[3][d];
    hh2 = bhh[128 + d] + pD[0][d] + pD[1][d] + pD[2][d] + pD[3][d];
  }
  __syncthreads();                               // s4
  {
    float g0 = 0.f, g1 = 0.f, g2 = 0.f;
    for (int c = c0; c < c0 + 16; ++c) {
      const float uc = ush[c];
      g0 += uc * wih[c * 192 + d];
      g1 += uc * wih[c * 192 + 64 + d];
      g2 += uc * wih[c * 192 + 128 + d];
    }
    pA[cq][d] = g0; pB[cq][d] = g1; pC[cq][d] = g2;
  }
  __syncthreads();                               // s5
  if (cq == 0) {
    const float gi0 = bih[d] + pA[0][d] + pA[1][d] + pA[2][d] + pA[3][d];
    const float gi1 = bih[64 + d] + pB[0][d] + pB[1][d] + pB[2][d] + pB[3][d];
    const float gi2 = bih[128 + d] + pC[0][d] + pC[1][d] + pC[2][d] + pC[3][d];
    const float rg = 1.f / (1.f + __expf(-(gi0 + hh0)));
    const float zg = 1.f / (1.f + __expf(-(gi1 + hh1)));
    const float ng = tanhf(gi2 + rg * hh2);
    const float sn = (1.f - zg) * ng + zg * prev;
    const float mm = wsum64(sn) * (1.f / 64.f);
    const float df = sn - mm;
    const float vv = wsum64(df * df) * (1.f / 64.f);
    const float rr = 1.f / sqrtf(vv + LN_EPS);
    snsh[d] = sn;
    hsh[d] = df * rr * lnfw[d] + lnfb[d];
  }
  __syncthreads();                               // s6
  {
    const int j = tid & 127, ch2 = tid >> 7;
    float a = 0.f;
    for (int c = ch2 * 32; c < ch2 * 32 + 32; ++c) a += hsh[c] * w1[c * 128 + j];
    hid1[ch2][j] = a;
  }
  __syncthreads();                               // s7
  {
    float o = 0.f;
    for (int j2 = cq * 32; j2 < cq * 32 + 32; ++j2) {
      const float hv = fmaxf(hid1[0][j2] + hid1[1][j2] + b1[j2], 0.f);
      o += hv * w2[j2 * 64 + d];
    }
    pA[cq][d] = o;
  }
  __syncthreads();                               // s8
  float news = 0.f;
  if (cq == 0) {
    news = snsh[d] + b2[d] + pA[0][d] + pA[1][d] + pA[2][d] + pA[3][d];
    slots_out[bk_i * 64 + d] = news;
  }
  if (!do_prep) return;
  // ---- fused q-prep for next iteration ----
  if (cq == 0) {
    const float mm = wsum64(news) * (1.f / 64.f);
    const float df = news - mm;
    const float vv = wsum64(df * df) * (1.f / 64.f);
    const float rr = 1.f / sqrtf(vv + LN_EPS);
    xsh[d] = df * rr * lnsw[d] + lnsb[d];
  }
  __syncthreads();                               // s9
  {
    float qpt = 0.f;
    for (int c = c0; c < c0 + 16; ++c) qpt += xsh[c] * wq[c * 64 + d];
    pB[cq][d] = qpt;
  }
  __syncthreads();                               // s10
  if (cq == 0) qsh[d] = bq[d] + pB[0][d] + pB[1][d] + pB[2][d] + pB[3][d];
  __syncthreads();                               // s11
  {
    float qq = 0.f;
    for (int dd2 = c0; dd2 < c0 + 16; ++dd2) qq += wk[d * 64 + dd2] * qsh[dd2];
    pC[cq][d] = qq;
  }
  __syncthreads();                               // s12
  if (cq == 0) {
    const float qpv = pC[0][d] + pC[1][d] + pC[2][d] + pC[3][d];
    const float c0v = wsum64(qsh[d] * bkv[d]);
    const float qw = qpv * lniw[d] * SCALE;
    const float As = wsum64(qw);
    const float Bp = wsum64(qpv * lnib[d]);
    const float Bc = (Bp + c0v) * SCALE;
    float* rec = qprep + b * REC;
    rec[d * 8 + kk] = qw;
    if (d == 0) { rec[512 + kk] = As; rec[520 + kk] = Bc; }
  }
}

extern "C" void kernel_launch(void* const* d_in, const int* in_sizes, int n_in,
                              void* d_out, int out_size, void* d_ws, size_t ws_size,
                              hipStream_t stream) {
  const float* inp   = (const float*)d_in[0];
  const float* noise = (const float*)d_in[1];
  const float* mu    = (const float*)d_in[2];
  const float* sg    = (const float*)d_in[3];
  const float* lniw  = (const float*)d_in[4];
  const float* lnib  = (const float*)d_in[5];
  const float* lnsw  = (const float*)d_in[6];
  const float* lnsb  = (const float*)d_in[7];
  const float* lnfw  = (const float*)d_in[8];
  const float* lnfb  = (const float*)d_in[9];
  const float* wk    = (const float*)d_in[10];
  const float* bk    = (const float*)d_in[11];
  const float* wq    = (const float*)d_in[12];
  const float* bq    = (const float*)d_in[13];
  const float* wv    = (const float*)d_in[14];
  const float* bv    = (const float*)d_in[15];
  const float* wih   = (const float*)d_in[16];
  const float* bih   = (const float*)d_in[17];
  const float* whh   = (const float*)d_in[18];
  const float* bhh   = (const float*)d_in[19];
  const float* w1    = (const float*)d_in[20];
  const float* b1    = (const float*)d_in[21];
  const float* w2    = (const float*)d_in[22];
  const float* b2    = (const float*)d_in[23];
  float* ws = (float*)d_ws;
  float* slots = ws;                              // 32768
  float* qprep = ws + 32768;                      // 64*528 = 33792
  float* part  = ws + 32768 + 64 * REC;           // 1024*528 = 540672
  float* out   = (float*)d_out;
  init_slots<<<64, 512, 0, stream>>>(noise, mu, sg, slots);
  prep_q<<<B_ * K_, 64, 0, stream>>>(slots, lnsw, lnsb, wq, bq, wk, bk, lniw, lnib, qprep);
  for (int it = 0; it < 3; ++it) {
    attn_pass<<<B_ * CHUNKS, 256, 0, stream>>>(inp, qprep, part);
    slot_update<<<B_ * K_, 256, 0, stream>>>(
        part, slots, lniw, lnib, wv, bv, wih, bih, whh, bhh,
        lnfw, lnfb, w1, b1, w2, b2, lnsw, lnsb, wq, bq, wk, bk,
        (it == 2) ? out : slots, qprep, (it < 2) ? 1 : 0);
  }
}